// Round 13
// baseline (1919.521 us; speedup 1.0000x reference)
//
#include <hip/hip_runtime.h>
#include <hip/hip_bf16.h>
#include <math.h>

constexpr int N_NODES = 200000;
constexpr int E_EDGES = 3200000;
constexpr int F_IN    = 128;
constexpr int D       = 64;
constexpr int G_GRAPHS = 512;
constexpr int T_OUT   = 10;

constexpr int SCAN_CHUNK   = 2048;
constexpr int SCAN_NBLOCKS = (N_NODES + SCAN_CHUNK - 1) / SCAN_CHUNK; // 98

constexpr int NPASS = 4;
constexpr int PASS_RANGE = N_NODES / NPASS;   // 50000

// ------------------------------------------------ degree (range-filtered)
__global__ __launch_bounds__(256) void deg_pass(const int* __restrict__ dst,
                                                int* __restrict__ deg,
                                                int lo, int hi) {
    int e0 = (blockIdx.x * 256 + threadIdx.x) * 4;
    if (e0 >= E_EDGES) return;
    int4 d4 = *(const int4*)(dst + e0);
    const int* dp = (const int*)&d4;
    #pragma unroll
    for (int i = 0; i < 4; ++i) {
        int d = dp[i];
        if (d >= lo && d < hi) atomicAdd(&deg[d], 1);
    }
}

__global__ __launch_bounds__(256) void dis_kernel(const int* __restrict__ deg,
                                                  float* __restrict__ dis) {
    int i = blockIdx.x * 256 + threadIdx.x;
    if (i < N_NODES) dis[i] = 1.0f / sqrtf((float)deg[i] + 1.0f);
}

// ----------------------------------------------------- 3-phase parallel scan
__global__ __launch_bounds__(256) void scan_p1(const int* __restrict__ deg,
                                               int* __restrict__ bsum) {
    const int b = blockIdx.x, t = threadIdx.x;
    int idx0 = b * SCAN_CHUNK + t * 8;
    int s = 0;
    #pragma unroll
    for (int i = 0; i < 8; ++i) {
        int idx = idx0 + i;
        if (idx < N_NODES) s += deg[idx];
    }
    #pragma unroll
    for (int off = 32; off; off >>= 1) s += __shfl_down(s, off, 64);
    __shared__ int ws[4];
    if ((t & 63) == 0) ws[t >> 6] = s;
    __syncthreads();
    if (t == 0) bsum[b] = ws[0] + ws[1] + ws[2] + ws[3];
}

__global__ __launch_bounds__(128) void scan_p2(int* __restrict__ bsum,
                                               int* __restrict__ row_ptr) {
    __shared__ int tmp[128];
    const int t = threadIdx.x;
    int v = (t < SCAN_NBLOCKS) ? bsum[t] : 0;
    tmp[t] = v;
    __syncthreads();
    #pragma unroll
    for (int off = 1; off < 128; off <<= 1) {
        int u = (t >= off) ? tmp[t - off] : 0;
        __syncthreads();
        tmp[t] += u;
        __syncthreads();
    }
    if (t < SCAN_NBLOCKS) bsum[t] = tmp[t] - v;   // exclusive
    if (t == 0) row_ptr[N_NODES] = E_EDGES;
}

__global__ __launch_bounds__(256) void scan_p3(const int* __restrict__ deg,
                                               const int* __restrict__ bsum,
                                               int* __restrict__ row_ptr) {
    const int b = blockIdx.x, t = threadIdx.x;
    int idx0 = b * SCAN_CHUNK + t * 8;
    int loc[8];
    int s = 0;
    #pragma unroll
    for (int i = 0; i < 8; ++i) {
        int idx = idx0 + i;
        loc[i] = (idx < N_NODES) ? deg[idx] : 0;
        s += loc[i];
    }
    __shared__ int tmp[256];
    tmp[t] = s;
    __syncthreads();
    #pragma unroll
    for (int off = 1; off < 256; off <<= 1) {
        int u = (t >= off) ? tmp[t - off] : 0;
        __syncthreads();
        tmp[t] += u;
        __syncthreads();
    }
    int run = tmp[t] - s + bsum[b];
    #pragma unroll
    for (int i = 0; i < 8; ++i) {
        int idx = idx0 + i;
        if (idx < N_NODES) row_ptr[idx] = run;
        run += loc[i];
    }
}

// ------------------------------------------------ placement (range-filtered)
__global__ __launch_bounds__(256) void place_pass(const int* __restrict__ src,
                                                  const int* __restrict__ dst,
                                                  const int* __restrict__ row_ptr,
                                                  int* __restrict__ cursor,
                                                  int* __restrict__ csr_src,
                                                  int lo, int hi) {
    int e0 = (blockIdx.x * 256 + threadIdx.x) * 4;
    if (e0 >= E_EDGES) return;
    int4 d4 = *(const int4*)(dst + e0);
    const int* dp = (const int*)&d4;
    #pragma unroll
    for (int i = 0; i < 4; ++i) {
        int d = dp[i];
        if (d >= lo && d < hi) {
            int pos = row_ptr[d] + atomicAdd(&cursor[d], 1);
            csr_src[pos] = src[e0 + i];
        }
    }
}

// ------------------------------------------- combined bias b' = Wmax@bc + bmax
__global__ __launch_bounds__(256) void bprime_kernel(const float* __restrict__ Wmax,
                                                     const float* __restrict__ bmax,
                                                     const float* __restrict__ bc0,
                                                     const float* __restrict__ bc1,
                                                     const float* __restrict__ bc2,
                                                     const float* __restrict__ bc3,
                                                     float* __restrict__ bprime) {
    const int l = threadIdx.x >> 6, c = threadIdx.x & 63;
    const float* bc = (l == 0) ? bc0 : (l == 1) ? bc1 : (l == 2) ? bc2 : bc3;
    float s = bmax[c];
    const float* w = Wmax + c * D;
    #pragma unroll
    for (int k = 0; k < D; k += 4) {
        float4 wv = *(const float4*)(w + k);
        float4 bv = *(const float4*)(bc + k);
        s += wv.x * bv.x + wv.y * bv.y + wv.z * bv.z + wv.w * bv.w;
    }
    bprime[l * D + c] = s;
}

// ---------------------------------------------------------------- GEMM (layer0)
// out[r][c] = dis[r] * sum_k in[r][k] * W[c][k];  64x64 per block, 256 thr.
template<int K>
__global__ __launch_bounds__(256) void gemm_k(const float* __restrict__ in,
                                              const float* __restrict__ W,
                                              float* __restrict__ out,
                                              const float* __restrict__ dis) {
    constexpr int GPR = K / 4;
    __shared__ float Xs[64 * K];
    __shared__ float Ws[D * K];
    __shared__ float ds[64];
    const int tid = threadIdx.x;
    const size_t row0 = (size_t)blockIdx.x * 64;

    for (int li = tid; li < 64 * GPR; li += 256) {
        int r = li / GPR, g = li % GPR;
        float4 v = *(const float4*)(in + (row0 + r) * K + g * 4);
        int gs = g ^ ((r >> 2) & 7);
        *(float4*)(Xs + r * K + gs * 4) = v;
    }
    for (int li = tid; li < D * GPR; li += 256) {
        int r = li / GPR, g = li % GPR;
        float4 v = *(const float4*)(W + r * K + g * 4);
        int gs = g ^ ((r >> 2) & 7);
        *(float4*)(Ws + r * K + gs * 4) = v;
    }
    if (tid < 64) ds[tid] = dis[row0 + tid];
    __syncthreads();

    const int lane = tid & 63;
    const int wave = tid >> 6;
    const int rg = lane & 15;
    const int cg = wave * 4 + (lane >> 4);
    float acc[4][4] = {};
    #pragma unroll 8
    for (int kq = 0; kq < GPR; ++kq) {
        float4 xv[4], wv[4];
        #pragma unroll
        for (int i = 0; i < 4; ++i)
            xv[i] = *(const float4*)(Xs + (rg * 4 + i) * K + ((kq ^ (rg & 7)) * 4));
        #pragma unroll
        for (int j = 0; j < 4; ++j)
            wv[j] = *(const float4*)(Ws + (cg * 4 + j) * K + ((kq ^ (cg & 7)) * 4));
        #pragma unroll
        for (int i = 0; i < 4; ++i)
            #pragma unroll
            for (int j = 0; j < 4; ++j)
                acc[i][j] += xv[i].x * wv[j].x + xv[i].y * wv[j].y +
                             xv[i].z * wv[j].z + xv[i].w * wv[j].w;
    }
    #pragma unroll
    for (int i = 0; i < 4; ++i) {
        size_t r = row0 + rg * 4 + i;
        float sc = ds[rg * 4 + i];
        float4 o = make_float4(acc[i][0] * sc, acc[i][1] * sc,
                               acc[i][2] * sc, acc[i][3] * sc);
        *(float4*)(out + r * D + cg * 4) = o;
    }
}

// --------------------------------------------- fused agg + double-GEMM + pool
// Per 64-row block:
//   gather phase: A-tile = dis_v * (L[v] + sum_{s in N(v)} L[s])  -> Xs (swizzled)
//   T = relu(A @ Wmax^T + b')   [LDS only]
//   segmented max-pool into pooled[graph][layer*D + col]
//   H = (T @ Wcn^T) * dis       [next layer's gather operand]
template<bool HAS_NEXT>
__global__ __launch_bounds__(256) void fused3_kernel(const float* __restrict__ Lin,
                                                     const int* __restrict__ row_ptr,
                                                     const int* __restrict__ csr_src,
                                                     const float* __restrict__ dis,
                                                     const float* __restrict__ Wmax,
                                                     const float* __restrict__ Wcn,
                                                     const float* __restrict__ bprime,
                                                     const int* __restrict__ batch,
                                                     int* __restrict__ pooled,
                                                     float* __restrict__ Lout,
                                                     int layer) {
    __shared__ float Xs[64 * D];   // A tile, then T tile (same swizzled layout)
    __shared__ float Ws[64 * D];   // Wmax
    __shared__ float Ws2[64 * D];  // Wc_next
    __shared__ int   bs[64];
    __shared__ float ds[64];
    __shared__ float bb[64];
    const int tid = threadIdx.x;
    const size_t row0 = (size_t)blockIdx.x * 64;
    const int lane = tid & 63;
    const int wave = tid >> 6;

    // stage weights / bias / batch (no barrier needed until Xs is consumed)
    for (int li = tid; li < 64 * 16; li += 256) {
        int r = li >> 4, g = li & 15;
        float4 v = *(const float4*)(Wmax + r * D + g * 4);
        *(float4*)(Ws + r * D + ((g ^ ((r >> 2) & 7)) * 4)) = v;
    }
    if (HAS_NEXT)
        for (int li = tid; li < 64 * 16; li += 256) {
            int r = li >> 4, g = li & 15;
            float4 v = *(const float4*)(Wcn + r * D + g * 4);
            *(float4*)(Ws2 + r * D + ((g ^ ((r >> 2) & 7)) * 4)) = v;
        }
    if (tid < 64) {
        bs[tid] = batch[row0 + tid];
        bb[tid] = bprime[tid];
        if (HAS_NEXT) ds[tid] = dis[row0 + tid];
    }

    // gather+aggregate: wave w owns nodes [w*16, w*16+16), lane = feature
    {
        const int swzg = lane >> 2;    // this lane's float4-granule
        const int e    = lane & 3;
        for (int n = 0; n < 16; ++n) {
            const int v = wave * 16 + n;             // wave-uniform
            const size_t vg = row0 + v;
            const int beg = row_ptr[vg];
            const int end = row_ptr[vg + 1];
            float a = Lin[vg * D + lane];            // self loop
            int p = beg;
            for (; p + 4 <= end; p += 4) {           // 4 independent row-fetches
                int s0 = csr_src[p + 0], s1 = csr_src[p + 1];
                int s2 = csr_src[p + 2], s3 = csr_src[p + 3];
                float r0 = Lin[(size_t)s0 * D + lane];
                float r1 = Lin[(size_t)s1 * D + lane];
                float r2 = Lin[(size_t)s2 * D + lane];
                float r3 = Lin[(size_t)s3 * D + lane];
                a += r0 + r1 + r2 + r3;
            }
            for (; p < end; ++p)
                a += Lin[(size_t)csr_src[p] * D + lane];
            a *= dis[vg];
            Xs[v * D + ((swzg ^ ((v >> 2) & 7)) * 4) + e] = a;
        }
    }
    __syncthreads();

    const int rg = lane & 15;
    const int cg = wave * 4 + (lane >> 4);

    // phase 2: acc = A @ Wmax^T
    float acc[4][4] = {};
    #pragma unroll 8
    for (int kq = 0; kq < 16; ++kq) {
        float4 xv[4], wv[4];
        #pragma unroll
        for (int i = 0; i < 4; ++i)
            xv[i] = *(const float4*)(Xs + (rg * 4 + i) * D + ((kq ^ (rg & 7)) * 4));
        #pragma unroll
        for (int j = 0; j < 4; ++j)
            wv[j] = *(const float4*)(Ws + (cg * 4 + j) * D + ((kq ^ (cg & 7)) * 4));
        #pragma unroll
        for (int i = 0; i < 4; ++i)
            #pragma unroll
            for (int j = 0; j < 4; ++j)
                acc[i][j] += xv[i].x * wv[j].x + xv[i].y * wv[j].y +
                             xv[i].z * wv[j].z + xv[i].w * wv[j].w;
    }

    // phase 3: T = relu(acc + b') -> back into Xs (same swizzled layout)
    __syncthreads();                 // all phase-2 reads of Xs complete
    #pragma unroll
    for (int i = 0; i < 4; ++i) {
        float4 o;
        float* op = (float*)&o;
        #pragma unroll
        for (int j = 0; j < 4; ++j)
            op[j] = fmaxf(acc[i][j] + bb[cg * 4 + j], 0.0f);
        *(float4*)(Xs + (rg * 4 + i) * D + ((cg ^ (rg & 7)) * 4)) = o;
    }
    __syncthreads();

    // pooling: wave 0, one column per thread, segmented over sorted batch
    if (tid < 64) {
        const int col = tid;
        const int cgr = col >> 2, ce = col & 3;
        float m = Xs[cgr * 4 + ce];        // row 0: (r>>2)&7 == 0
        int bg = bs[0];
        #pragma unroll 8
        for (int r = 1; r < 64; ++r) {
            int b2 = bs[r];
            float v = Xs[r * D + ((cgr ^ ((r >> 2) & 7)) * 4) + ce];
            if (b2 != bg) {
                atomicMax(&pooled[bg * (4 * D) + layer * D + col], __float_as_int(m));
                bg = b2; m = v;
            } else {
                m = fmaxf(m, v);
            }
        }
        atomicMax(&pooled[bg * (4 * D) + layer * D + col], __float_as_int(m));
    }

    // phase 4: H = (T @ Wcn^T) * dis
    if (HAS_NEXT) {
        float acc2[4][4] = {};
        #pragma unroll 8
        for (int kq = 0; kq < 16; ++kq) {
            float4 xv[4], wv[4];
            #pragma unroll
            for (int i = 0; i < 4; ++i)
                xv[i] = *(const float4*)(Xs + (rg * 4 + i) * D + ((kq ^ (rg & 7)) * 4));
            #pragma unroll
            for (int j = 0; j < 4; ++j)
                wv[j] = *(const float4*)(Ws2 + (cg * 4 + j) * D + ((kq ^ (cg & 7)) * 4));
            #pragma unroll
            for (int i = 0; i < 4; ++i)
                #pragma unroll
                for (int j = 0; j < 4; ++j)
                    acc2[i][j] += xv[i].x * wv[j].x + xv[i].y * wv[j].y +
                                  xv[i].z * wv[j].z + xv[i].w * wv[j].w;
        }
        #pragma unroll
        for (int i = 0; i < 4; ++i) {
            size_t r = row0 + rg * 4 + i;
            float sc = ds[rg * 4 + i];
            float4 o = make_float4(acc2[i][0] * sc, acc2[i][1] * sc,
                                   acc2[i][2] * sc, acc2[i][3] * sc);
            *(float4*)(Lout + r * D + cg * 4) = o;
        }
    }
}

// ---------------------------------------------------------------- final MLP
__global__ __launch_bounds__(64) void mlp_kernel(const float* __restrict__ pooled,
                                                 const float* __restrict__ W1,
                                                 const float* __restrict__ b1,
                                                 const float* __restrict__ W2,
                                                 const float* __restrict__ b2,
                                                 float* __restrict__ out) {
    __shared__ float ps[4 * D];
    __shared__ float hs[D];
    const int g = blockIdx.x, t = threadIdx.x;
    *(float4*)(ps + t * 4) = *(const float4*)(pooled + (size_t)g * (4 * D) + t * 4);
    __syncthreads();
    float acc = b1[t];
    const float* w = W1 + (size_t)t * (4 * D);
    #pragma unroll 4
    for (int k = 0; k < 4 * D; k += 4) {
        float4 wv = *(const float4*)(w + k);
        float4 pv = *(const float4*)(ps + k);
        acc += wv.x * pv.x + wv.y * pv.y + wv.z * pv.z + wv.w * pv.w;
    }
    hs[t] = fmaxf(acc, 0.0f);
    __syncthreads();
    if (t < T_OUT) {
        float o = b2[t];
        const float* w2 = W2 + t * D;
        #pragma unroll
        for (int k = 0; k < D; ++k) o += hs[k] * w2[k];
        out[(size_t)g * T_OUT + t] = o;
    }
}

// ---------------------------------------------------------------- launch
extern "C" void kernel_launch(void* const* d_in, const int* in_sizes, int n_in,
                              void* d_out, int out_size, void* d_ws, size_t ws_size,
                              hipStream_t stream) {
    (void)in_sizes; (void)n_in; (void)out_size; (void)ws_size;
    const float* x     = (const float*)d_in[0];
    const int*   ei    = (const int*)d_in[1];
    const int*   batch = (const int*)d_in[2];
    const float* Wc[4] = {(const float*)d_in[4], (const float*)d_in[6],
                          (const float*)d_in[8], (const float*)d_in[10]};
    const float* bc[4] = {(const float*)d_in[5], (const float*)d_in[7],
                          (const float*)d_in[9], (const float*)d_in[11]};
    const float* Wmax = (const float*)d_in[12];
    const float* bmax = (const float*)d_in[13];
    const float* W1   = (const float*)d_in[14];
    const float* b1   = (const float*)d_in[15];
    const float* W2   = (const float*)d_in[16];
    const float* b2   = (const float*)d_in[17];
    float* out = (float*)d_out;

    float* fws = (float*)d_ws;
    size_t off = 0;
    float* bufA     = fws + off; off += (size_t)N_NODES * D;
    float* bufB     = fws + off; off += (size_t)N_NODES * D;
    int*   csr_src  = (int*)(fws + off); off += E_EDGES;
    int*   row_ptr  = (int*)(fws + off); off += N_NODES + 16;
    int*   deg      = (int*)(fws + off); off += N_NODES;
    int*   cursor   = (int*)(fws + off); off += N_NODES;
    float* dis      = fws + off; off += N_NODES;
    int*   pooled   = (int*)(fws + off); off += G_GRAPHS * 4 * D;
    int*   bsum     = (int*)(fws + off); off += SCAN_NBLOCKS + 16;
    float* bprime   = fws + off; off += 4 * D;

    const int* srcI = ei;
    const int* dstI = ei + E_EDGES;

    hipMemsetAsync(deg,    0, sizeof(int) * 2 * N_NODES, stream);  // deg + cursor
    hipMemsetAsync(pooled, 0, sizeof(int) * G_GRAPHS * 4 * D, stream);

    for (int p = 0; p < NPASS; ++p)
        deg_pass<<<E_EDGES / (256 * 4), 256, 0, stream>>>(dstI, deg,
                                                          p * PASS_RANGE,
                                                          (p + 1) * PASS_RANGE);
    dis_kernel<<<(N_NODES + 255) / 256, 256, 0, stream>>>(deg, dis);
    scan_p1<<<SCAN_NBLOCKS, 256, 0, stream>>>(deg, bsum);
    scan_p2<<<1, 128, 0, stream>>>(bsum, row_ptr);
    scan_p3<<<SCAN_NBLOCKS, 256, 0, stream>>>(deg, bsum, row_ptr);
    for (int p = 0; p < NPASS; ++p)
        place_pass<<<E_EDGES / (256 * 4), 256, 0, stream>>>(srcI, dstI, row_ptr,
                                                            cursor, csr_src,
                                                            p * PASS_RANGE,
                                                            (p + 1) * PASS_RANGE);
    bprime_kernel<<<1, 256, 0, stream>>>(Wmax, bmax, bc[0], bc[1], bc[2], bc[3],
                                         bprime);

    // layer 0 conv GEMM: bufA = (x @ Wc0^T) * dis
    gemm_k<F_IN><<<N_NODES / 64, 256, 0, stream>>>(x, Wc[0], bufA, dis);

    const float* cur = bufA;
    float*       nxt = bufB;
    for (int l = 0; l < 4; ++l) {
        if (l < 3) {
            fused3_kernel<true><<<N_NODES / 64, 256, 0, stream>>>(
                cur, row_ptr, csr_src, dis, Wmax, Wc[l + 1], bprime + l * D,
                batch, pooled, nxt, l);
            const float* t = cur; cur = nxt; nxt = (float*)t;
        } else {
            fused3_kernel<false><<<N_NODES / 64, 256, 0, stream>>>(
                cur, row_ptr, csr_src, dis, Wmax, nullptr, bprime + l * D,
                batch, pooled, nullptr, l);
        }
    }
    mlp_kernel<<<G_GRAPHS, 64, 0, stream>>>((const float*)pooled, W1, b1, W2, b2, out);
}